// Round 14
// baseline (789.071 us; speedup 1.0000x reference)
//
#include <hip/hip_runtime.h>
#include <stdint.h>

#define HH   128
#define NLAY 3
#define RR   32
#define OO   48
#define BBX  64
#define FFX  32
#define LLX  (RR + OO - 1)    /* 79 */
#define RBr  (RR * BBX)       /* 2048 */
#define N6   (6 * HH)         /* 768 */
#define TSTEPS (LLX + NLAY - 1)  /* 81 */
#define NBLOCKS 192

typedef unsigned short u16;
typedef __attribute__((ext_vector_type(8))) short short8;
typedef __attribute__((ext_vector_type(4))) float f32x4;

// ---- workspace layout ----
#define OFF_ABUF0 ((size_t)0)
#define SZ_ABUF0  ((size_t)LLX * RBr * FFX * 2)
#define OFF_HZ    (OFF_ABUF0 + SZ_ABUF0)
#define SZ_HZ     ((size_t)NLAY * 2 * RBr * 256 * 2)   /* [l][slot][2048][256] bf16 */
#define OFF_BAR   (OFF_HZ + SZ_HZ)
#define SZ_BAR    ((size_t)32768)
/* barG @+0, table @+256, arrival @+4096 (+bblk*2048, 24 slots x 64B),
   epoch @+24576 (+bblk*256) */
#define SZ_STATE  (SZ_HZ + SZ_BAR)

__device__ __forceinline__ u16 f2b(float x) {
  uint32_t u = __float_as_uint(x);
  return (u16)((u + 0x7FFFu + ((u >> 16) & 1u)) >> 16);
}
__device__ __forceinline__ float rcp_(float x) { return __builtin_amdgcn_rcpf(x); }
__device__ __forceinline__ float sigmoidf_(float x) {
  return rcp_(1.0f + __expf(-x));
}
__device__ __forceinline__ float tanhf_(float x) {
  return 1.0f - 2.0f * rcp_(__expf(2.0f * x) + 1.0f);
}

__global__ __launch_bounds__(256) void k_prep_input(const float* __restrict__ inp,
                                                    u16* __restrict__ abuf0) {
  int idx = blockIdx.x * 256 + threadIdx.x;
  if (idx >= LLX * RBr * FFX) return;
  int f   = idx & (FFX - 1);
  int row = (idx >> 5) & (RBr - 1);
  int s   = idx / (RBr * FFX);
  int g = row >> 6, b = row & 63;
  int o = s - g;
  float v = (o >= 0 && o < OO) ? inp[((b * RR + g) * OO + o) * FFX + f] : 0.0f;
  abuf0[idx] = f2b(v);
}

__global__ __launch_bounds__(256) void k_zero(uint32_t* __restrict__ p, size_t nwords) {
  size_t i = (size_t)blockIdx.x * 256 + threadIdx.x;
  size_t stride = (size_t)gridDim.x * 256;
  for (; i < nwords; i += stride) p[i] = 0u;
}

// ---- stage W into LDS in MFMA fragment-consumption order (conflict-free) ----
template <int KK>
__device__ __forceinline__ void stage_w(const float* __restrict__ Wsrc, int jblk,
                                        u16* __restrict__ Wl) {
  constexpr int NFRAG = (KK / 32) * 6;     // 54 or 96
  for (int e = threadIdx.x; e < NFRAG * 64; e += 512) {
    int kcm = e >> 6, ln = e & 63;
    int kc = kcm / 6, m = kcm - kc * 6;
    int fr2 = ln & 15, hi2 = ln >> 4;
    int srow = m * 128 + jblk * 16 + fr2;
    const float* src = Wsrc + (size_t)srow * KK + kc * 32 + hi2 * 8;
    short8 v;
#pragma unroll
    for (int x = 0; x < 8; ++x) v[x] = (short)f2b(src[x]);
    *(short8*)&Wl[(size_t)e * 8] = v;
  }
}

template <int KK>
__device__ __forceinline__ void persist_body(char* __restrict__ ws,
                                             const float* __restrict__ Bias_l,
                                             float* __restrict__ out,
                                             int layer, int jblk, int bblk, bool light,
                                             u16* __restrict__ Wl,
                                             float* __restrict__ hcl,
                                             uint32_t* __restrict__ arrC,
                                             uint32_t* __restrict__ epoC,
                                             bool leader) {
  constexpr int NCH = KK / 32;
  constexpr int RD  = 3;                         // per-tile A ring (6 loads in flight)
  const int tid = threadIdx.x;
  const int lane = tid & 63, w = tid >> 6;       // 8 waves: wave owns groups {4w..4w+3}
  const int fr = lane & 15, hi = lane >> 4;
  const int myslot = layer * 8 + jblk;

  const int bcol = bblk * 8 + (fr & 7);
  // tile t in {0,1}: fragment rows for groups {4w+2t, 4w+2t+1}
  const int g00   = w * 4 + (fr >> 3);           // tile 0
  const int arow0 = g00 * 64 + bcol;
  const int arp0  = ((g00 + 1) & 31) * 64 + bcol;
  const int g01   = g00 + 2;                     // tile 1
  const int arow1 = g01 * 64 + bcol;
  const int arp1  = ((g01 + 1) & 31) * 64 + bcol;
  const int j = jblk * 16 + fr;
  const u16* wfrag = &Wl[lane * 8];
  float bia[6];
#pragma unroll
  for (int m = 0; m < 6; ++m) bia[m] = Bias_l[m * 128 + j];

  u16*   hz_base  = (u16*)(ws + OFF_HZ) + (size_t)layer * 2 * RBr * 256;
  u16*   hzp_base = (u16*)(ws + OFF_HZ) + (size_t)(layer - 1) * 2 * RBr * 256;
  u16*   abuf0    = (u16*)(ws + OFF_ABUF0);
  float* hid_row  = out + (size_t)RBr * LLX * 256;
  float* hid_col  = hid_row + (size_t)BBX * NLAY * RR * HH;

  float hr_reg[2][4];
#pragma unroll
  for (int t2 = 0; t2 < 2; ++t2)
#pragma unroll
    for (int q = 0; q < 4; ++q) hr_reg[t2][q] = 0.0f;

  for (int t = 0; t < TSTEPS; ++t) {
    const int s = t - layer;
    const uint32_t target = (uint32_t)(t + 1);
    float sv_r[2][4], sv_c[2][4];                // out/hid values, stored post-arrival
#pragma unroll
    for (int t2 = 0; t2 < 2; ++t2)
#pragma unroll
      for (int q = 0; q < 4; ++q) { sv_r[t2][q] = 0.0f; sv_c[t2][q] = 0.0f; }

    if (s >= 0 && s < LLX) {
      const int sW = s & 1, sR = sW ^ 1;
      const u16* hzR = hz_base + (size_t)sR * RBr * 256;
      u16*       hzW = hz_base + (size_t)sW * RBr * 256;
      const u16* hzP = hzp_base + (size_t)sW * RBr * 256;  // prev layer, slice s
      const u16* ab_s = abuf0 + (size_t)s * RBr * FFX;
      const float* hcR = hcl + sR * 4352;
      float*       hcW = hcl + sW * 4352;

      if (w * 4 <= s) {
        // ---- active wave: dual-tile GEMM, W fragment read ONCE per 2 MFMAs ----
        // (tile 1 rows beyond the wavefront have all-zero inputs -> exact zeros)
        auto LDK = [&](int ar, int ap, int kc) -> short8 {
          if (kc < 8)
            return *(const short8*)&hzR[ar * 256 + kc * 32 + hi * 8];
          if constexpr (KK == 288) {
            return *(const short8*)&ab_s[ar * FFX + hi * 8];
          } else {
            if (kc < 12)
              return *(const short8*)&hzP[ar * 256 + (kc - 8) * 32 + hi * 8];
            return *(const short8*)&hzP[ap * 256 + 128 + (kc - 12) * 32 + hi * 8];
          }
        };

        f32x4 z4 = {0.f, 0.f, 0.f, 0.f};
        f32x4 acc0[6], acc1[6];
#pragma unroll
        for (int m = 0; m < 6; ++m) { acc0[m] = z4; acc1[m] = z4; }

        short8 ring0[RD], ring1[RD];
#pragma unroll
        for (int i = 0; i < RD; ++i) {
          ring0[i] = LDK(arow0, arp0, i);
          ring1[i] = LDK(arow1, arp1, i);
        }
        __builtin_amdgcn_s_setprio(1);
#pragma unroll
        for (int kc = 0; kc < NCH; ++kc) {
          short8 a0 = ring0[kc % RD];
          short8 a1 = ring1[kc % RD];
          if (kc + RD < NCH) {
            ring0[kc % RD] = LDK(arow0, arp0, kc + RD);
            ring1[kc % RD] = LDK(arow1, arp1, kc + RD);
          }
#pragma unroll
          for (int m = 0; m < 6; ++m) {
            short8 bv = *(const short8*)&wfrag[(size_t)(kc * 6 + m) * 512];
            acc0[m] = __builtin_amdgcn_mfma_f32_16x16x32_bf16(a0, bv, acc0[m], 0, 0, 0);
            acc1[m] = __builtin_amdgcn_mfma_f32_16x16x32_bf16(a1, bv, acc1[m], 0, 0, 0);
          }
        }
        __builtin_amdgcn_s_setprio(0);

        // ---- fused epilogue, both tiles ----
#pragma unroll
        for (int t2 = 0; t2 < 2; ++t2) {
          const int g = w * 4 + 2 * t2 + (hi >> 1);
          const int gp = (g + 1) & (RR - 1);
          const float msk = (g <= s && s < RR) ? 1.0f : 0.0f;
          float mb[6];
#pragma unroll
          for (int m = 0; m < 6; ++m) mb[m] = msk * bia[m];
#pragma unroll
          for (int q = 0; q < 4; ++q) {
            const f32x4* A = t2 ? acc1 : acc0;
            const int lb = (hi & 1) * 4 + q;
            const int b  = bblk * 8 + lb;
            const int row = g * 64 + b;
            const int lrow = g * 8 + lb;
            const int rp = gp * 64 + b;
            const int lrp = gp * 8 + lb;
            float ur  = sigmoidf_(A[0][q] + mb[0]);
            float orw = sigmoidf_(A[1][q] + mb[1]);
            float uc  = sigmoidf_(A[2][q] + mb[2]);
            float oc  = sigmoidf_(A[3][q] + mb[3]);
            float ir  = tanhf_(A[4][q] + mb[4]);
            float ic  = tanhf_(A[5][q] + mb[5]);
            float hr_o = hr_reg[t2][q];
            float hc_o = hcR[lrow * 17 + fr];
            float hr_n = tanhf_((1.0f - ur) * hr_o + ur * ir) * orw;
            float hc_n = tanhf_((1.0f - uc) * hc_o + uc * ic) * oc;
            hr_reg[t2][q] = hr_n;
            sv_r[t2][q] = hr_n;
            sv_c[t2][q] = hc_n;
            hcW[lrp * 17 + fr] = hc_n;
            hzW[row * 256 + j] = f2b(hr_n);
            hzW[rp * 256 + HH + j] = f2b(hc_n);
          }
        }
      } else {
        // -------- fully-inactive wave: state zeros now; out zeros later --------
#pragma unroll
        for (int t2 = 0; t2 < 2; ++t2) {
          const int g = w * 4 + 2 * t2 + (hi >> 1);
          const int gp = (g + 1) & (RR - 1);
#pragma unroll
          for (int q = 0; q < 4; ++q) {
            const int lb = (hi & 1) * 4 + q;
            const int b  = bblk * 8 + lb;
            const int row = g * 64 + b;
            const int rp = gp * 64 + b;
            const int lrp = gp * 8 + lb;
            hcW[lrp * 17 + fr] = 0.0f;
            hzW[row * 256 + j] = 0;
            hzW[rp * 256 + HH + j] = 0;
          }
        }
      }
    }

    // ---- arrive: all waves' hz/hcl state stores drained by syncthreads ----
    __syncthreads();
    if (tid == 0) {
      if (!light) __threadfence();
      __hip_atomic_store(&arrC[myslot * 16], target, __ATOMIC_RELAXED,
                         __HIP_MEMORY_SCOPE_AGENT);
    }

    // ---- post-arrival: out/hid stores (no consumer this step) ----
    if (s >= 0 && s < LLX) {
#pragma unroll
      for (int t2 = 0; t2 < 2; ++t2) {
        const int g = w * 4 + 2 * t2 + (hi >> 1);
#pragma unroll
        for (int q = 0; q < 4; ++q) {
          const int lb = (hi & 1) * 4 + q;
          const int b  = bblk * 8 + lb;
          const int row = g * 64 + b;
          if (layer == 2) {
            out[((size_t)row * LLX + s) * 256 + j] = sv_r[t2][q];
            out[((size_t)row * LLX + s) * 256 + HH + j] = sv_c[t2][q];
          }
          if (s - g == OO - 1)
            hid_row[((size_t)(b * NLAY + layer) * RR + g) * HH + j] = sv_r[t2][q];
          if (g == RR - 1 && s >= RR - 1)
            hid_col[((size_t)(b * NLAY + layer) * OO + (s - (RR - 1))) * HH + j] = sv_c[t2][q];
        }
      }
    }

    // ---- wait: leader gathers 24 slots in parallel, publishes epoch ----
    if (leader) {
      if (tid < 24) {
        while (__hip_atomic_load(&arrC[tid * 16], __ATOMIC_RELAXED,
                                 __HIP_MEMORY_SCOPE_AGENT) < target)
          __builtin_amdgcn_s_sleep(1);
      }
      __syncthreads();
      if (tid == 0)
        __hip_atomic_store(epoC, target, __ATOMIC_RELAXED, __HIP_MEMORY_SCOPE_AGENT);
    }
    if (tid == 0) {
      while (__hip_atomic_load(epoC, __ATOMIC_RELAXED, __HIP_MEMORY_SCOPE_AGENT) < target)
        __builtin_amdgcn_s_sleep(1);
      if (!light) __threadfence();
    }
    __syncthreads();
    if (light) asm volatile("buffer_inv" ::: "memory");
  }
}

__global__ __launch_bounds__(512) void k_persist(char* __restrict__ ws,
                                                 const float* __restrict__ Wf,
                                                 const float* __restrict__ Wo,
                                                 const float* __restrict__ Bias,
                                                 float* __restrict__ out) {
  __shared__ u16 Wl[49152];       // 96 KiB: W slice, fragment-contiguous
  __shared__ float hcl[8704];     // 34 KiB: hc state, dbuf, stride-17
  __shared__ uint32_t sh_light;
  const int bx = blockIdx.x;
  const int layer = bx >> 6, jblk = (bx >> 3) & 7, bblk = bx & 7;
  const int tid = threadIdx.x;

  if (layer == 0) stage_w<288>(Wf, jblk, Wl);
  else            stage_w<512>(Wo + (size_t)(layer - 1) * N6 * 512, jblk, Wl);
  for (int e = tid; e < 8704; e += 512) hcl[e] = 0.0f;

  // placement check: one-time global heavy barrier + per-component XCD match
  uint32_t xcc;
  asm volatile("s_getreg_b32 %0, hwreg(20, 0, 4)" : "=s"(xcc));
  uint32_t* barG  = (uint32_t*)(ws + OFF_BAR);
  uint32_t* table = (uint32_t*)(ws + OFF_BAR + 256);
  uint32_t* arrC  = (uint32_t*)(ws + OFF_BAR + 4096 + (size_t)bblk * 2048);
  uint32_t* epoC  = (uint32_t*)(ws + OFF_BAR + 24576 + (size_t)bblk * 256);
  const bool leader = (layer == 0 && jblk == 0);
  __syncthreads();
  if (tid == 0) {
    __hip_atomic_store(&table[bx], xcc, __ATOMIC_RELAXED, __HIP_MEMORY_SCOPE_AGENT);
    __hip_atomic_fetch_add(barG, 1u, __ATOMIC_RELEASE, __HIP_MEMORY_SCOPE_AGENT);
    while (__hip_atomic_load(barG, __ATOMIC_ACQUIRE, __HIP_MEMORY_SCOPE_AGENT) < NBLOCKS)
      __builtin_amdgcn_s_sleep(1);
    uint32_t lt = 1u;
    for (int q2 = 0; q2 < 24; ++q2) {
      uint32_t v = __hip_atomic_load(&table[q2 * 8 + bblk], __ATOMIC_RELAXED,
                                     __HIP_MEMORY_SCOPE_AGENT);
      lt &= (v == xcc) ? 1u : 0u;
    }
    sh_light = lt;
  }
  __syncthreads();
  const bool light = (sh_light != 0u);

  const float* bias_l = Bias + layer * N6;
  if (layer == 0)
    persist_body<288>(ws, bias_l, out, 0, jblk, bblk, light, Wl, hcl,
                      arrC, epoC, leader);
  else
    persist_body<512>(ws, bias_l, out, layer, jblk, bblk, light, Wl, hcl,
                      arrC, epoC, leader);
}

extern "C" void kernel_launch(void* const* d_in, const int* in_sizes, int n_in,
                              void* d_out, int out_size, void* d_ws, size_t ws_size,
                              hipStream_t stream) {
  const float* inp  = (const float*)d_in[0];
  const float* Wf   = (const float*)d_in[1];
  const float* Wo   = (const float*)d_in[2];
  const float* Bias = (const float*)d_in[3];
  float* out = (float*)d_out;
  char* ws = (char*)d_ws;
  (void)in_sizes; (void)n_in; (void)out_size; (void)ws_size;

  k_prep_input<<<(LLX * RBr * FFX) / 256, 256, 0, stream>>>(inp, (u16*)(ws + OFF_ABUF0));
  k_zero<<<2048, 256, 0, stream>>>((uint32_t*)(ws + OFF_HZ), SZ_STATE / 4);
  k_persist<<<NBLOCKS, 512, 0, stream>>>(ws, Wf, Wo, Bias, out);
}